// Round 2
// baseline (562.978 us; speedup 1.0000x reference)
//
#include <hip/hip_runtime.h>

// EdgeAttention for MI355X (gfx950) — two-kernel split.
// proj_kernel: P4 = Eflat @ [Wq|Wk|Wv1|Wv2]^T + bias (reads ef coalesced), writes
//   Q  (bf16, *1/sqrt(d) folded, per-(b,l) slice, row i*128+d)  -> A-frag-ready
//   K  (bf16, per-(b,l) slice, pre-swizzled LDS image)
//   V2T(bf16, per-(b,l) slice, d*256+j)
//   V1 (f32,  per-(b,l) slice, i*128+d)
// attn_kernel: per (b,l): stage K slice -> LDS, then per wave i-tile:
//   S = Q K^T -> softmax(j) -> (P V2) * V1 * inv -> Wo proj -> out.
// Fallback (ws too small): the round-1 fused kernel.
// MFMA layouts (m89/m91/m120-verified):
//   A-frag: a[j] = A[m = lane&15][k = (lane>>4)*8 + j]
//   B-frag: b[j] = B^T[n = lane&15][k = (lane>>4)*8 + j]   (dot-of-rows)
//   C/D   : c[r] = D[m = (lane>>4)*4 + r][n = lane&15]

typedef __bf16 bf16x8 __attribute__((ext_vector_type(8)));
typedef float  f32x4  __attribute__((ext_vector_type(4)));
typedef unsigned short u16x4 __attribute__((ext_vector_type(4)));

#define MFMA(a, b, c) __builtin_amdgcn_mfma_f32_16x16x32_bf16((a), (b), (c), 0, 0, 0)

// workspace layout (shorts unless noted)
#define SLICE 32768                      // elems per (b,l) slice (256*128)
static const size_t WS_Q    = 81920;                  // after 5 bf16 weight mats
static const size_t WS_K    = WS_Q + 16777216;        // 2*256 slices * 32768
static const size_t WS_V2T  = WS_K + 16777216;
static const size_t WS_V1_B = (WS_V2T + 16777216) * 2;  // byte offset of f32 V1
static const size_t WS_NEEDED = WS_V1_B + 67108864ull;  // + 2*256*32768 floats

__device__ __forceinline__ unsigned short rne_bf16(float f) {
  unsigned int u = __float_as_uint(f);
  u += 0x7fffu + ((u >> 16) & 1u);   // round-to-nearest-even
  return (unsigned short)(u >> 16);
}

__device__ __forceinline__ bf16x8 cvt_frag(const float* __restrict__ p) {
  f32x4 a = *(const f32x4*)p;
  f32x4 b = *(const f32x4*)(p + 4);
  union { bf16x8 v; unsigned short u[8]; } t;
  t.u[0] = rne_bf16(a[0]); t.u[1] = rne_bf16(a[1]);
  t.u[2] = rne_bf16(a[2]); t.u[3] = rne_bf16(a[3]);
  t.u[4] = rne_bf16(b[0]); t.u[5] = rne_bf16(b[1]);
  t.u[6] = rne_bf16(b[2]); t.u[7] = rne_bf16(b[3]);
  return t.v;
}

__global__ void cvt_weights(const float* __restrict__ Wq, const float* __restrict__ Wk,
                            const float* __restrict__ Wv1, const float* __restrict__ Wv2,
                            const float* __restrict__ Wo, unsigned short* __restrict__ ws) {
  int t = blockIdx.x * 256 + threadIdx.x;   // 0..16383
  ws[t]             = rne_bf16(Wq[t]);
  ws[16384 + t]     = rne_bf16(Wk[t]);
  ws[2 * 16384 + t] = rne_bf16(Wv1[t]);
  ws[3 * 16384 + t] = rne_bf16(Wv2[t]);
  ws[4 * 16384 + t] = rne_bf16(Wo[t]);
}

// ---------------------------------------------------------------------------
// Kernel P: 4 projections. grid 512 = (b,x); 512 thr = 8 waves; wave does 2
// y-tiles of 16 rows. For K/V2T the block's x IS l (writes to own slice);
// for Q/V1 the row's y IS l (strided full-line writes across slices).
// ---------------------------------------------------------------------------
__global__ __launch_bounds__(512, 4)
void proj_kernel(const float* __restrict__ ef, const unsigned short* __restrict__ wbf,
                 const float* __restrict__ bq, const float* __restrict__ bk,
                 const float* __restrict__ bv1, const float* __restrict__ bv2,
                 unsigned short* __restrict__ ws, float* __restrict__ v1f) {
  const int tid  = threadIdx.x;
  const int lane = tid & 63;
  const int wv   = tid >> 6;
  const int lc   = lane & 15;
  const int q4   = lane >> 4;
  const int b    = blockIdx.x >> 8;
  const int x    = blockIdx.x & 255;

  const unsigned short* WqB  = wbf;
  const unsigned short* WkB  = wbf + 16384;
  const unsigned short* Wv1B = wbf + 2 * 16384;
  const unsigned short* Wv2B = wbf + 3 * 16384;
  unsigned short* Qg   = ws + WS_Q;
  unsigned short* Kg   = ws + WS_K;
  unsigned short* V2Tg = ws + WS_V2T;

  const float scale = 0.08838834764831845f;  // 1/sqrt(128)
  const f32x4 Z4 = {0.f, 0.f, 0.f, 0.f};

  unsigned short* ks = Kg   + ((size_t)(b * 256 + x)) * SLICE;
  unsigned short* vs = V2Tg + ((size_t)(b * 256 + x)) * SLICE;

  #pragma unroll 1
  for (int mm = 0; mm < 2; ++mm) {
    const int y0 = (wv * 2 + mm) * 16;
    bf16x8 aF[4];
    const float* rp = ef + ((size_t)((b * 256 + x) * 256 + y0 + lc)) * 128 + q4 * 8;
    #pragma unroll
    for (int kc = 0; kc < 4; ++kc) aF[kc] = cvt_frag(rp + kc * 32);

    // ---- pass A: K + V2 ----
    {
      f32x4 accK[8], accV[8];
      #pragma unroll
      for (int n = 0; n < 8; ++n) { accK[n] = Z4; accV[n] = Z4; }
      #pragma unroll 1
      for (int kc = 0; kc < 4; ++kc) {
        #pragma unroll
        for (int n = 0; n < 8; ++n) {
          bf16x8 bwk = *(const bf16x8*)(WkB  + (n * 16 + lc) * 128 + kc * 32 + q4 * 8);
          bf16x8 bwv = *(const bf16x8*)(Wv2B + (n * 16 + lc) * 128 + kc * 32 + q4 * 8);
          accK[n] = MFMA(aF[kc], bwk, accK[n]);
          accV[n] = MFMA(aF[kc], bwv, accV[n]);
        }
      }
      #pragma unroll 1
      for (int n = 0; n < 8; ++n) {
        const int o = n * 16 + lc;
        const float bkv = bk[o];
        const float bvv = bv2[o];
        u16x4 pk;
        #pragma unroll
        for (int r = 0; r < 4; ++r) {
          const int j = y0 + q4 * 4 + r;
          ks[j * 128 + (((o >> 3) ^ (j & 15)) << 3) + (o & 7)] = rne_bf16(accK[n][r] + bkv);
          pk[r] = rne_bf16(accV[n][r] + bvv);
        }
        *(u16x4*)(vs + o * 256 + y0 + q4 * 4) = pk;   // 8B store, j-contig
      }
    }

    // ---- pass B: Q + V1 ----
    {
      f32x4 accQ[8], accV[8];
      #pragma unroll
      for (int n = 0; n < 8; ++n) { accQ[n] = Z4; accV[n] = Z4; }
      #pragma unroll 1
      for (int kc = 0; kc < 4; ++kc) {
        #pragma unroll
        for (int n = 0; n < 8; ++n) {
          bf16x8 bwq = *(const bf16x8*)(WqB  + (n * 16 + lc) * 128 + kc * 32 + q4 * 8);
          bf16x8 bwv = *(const bf16x8*)(Wv1B + (n * 16 + lc) * 128 + kc * 32 + q4 * 8);
          accQ[n] = MFMA(aF[kc], bwq, accQ[n]);
          accV[n] = MFMA(aF[kc], bwv, accV[n]);
        }
      }
      #pragma unroll 1
      for (int n = 0; n < 8; ++n) {
        const int o = n * 16 + lc;
        const float bqv  = bq[o];
        const float bv1v = bv1[o];
        #pragma unroll
        for (int r = 0; r < 4; ++r) {
          const int y = y0 + q4 * 4 + r;          // this row's l
          Qg[((size_t)(b * 256 + y)) * SLICE + x * 128 + o] =
              rne_bf16((accQ[n][r] + bqv) * scale);
          v1f[((size_t)(b * 256 + y)) * 32768 + x * 128 + o] = accV[n][r] + bv1v;
        }
      }
    }
  }
}

// ---------------------------------------------------------------------------
// Attention kernel. grid 512 = (b,l); 512 thr = 8 waves; 2 i-tiles per wave.
// ---------------------------------------------------------------------------
__global__ __launch_bounds__(512, 4)
void attn_kernel(const unsigned short* __restrict__ wbf, const float* __restrict__ bo,
                 const unsigned short* __restrict__ ws, const float* __restrict__ v1f,
                 float* __restrict__ out) {
  __shared__ unsigned short Kb[256 * 128];     // 64 KB, swizzled image
  __shared__ unsigned short chunk[8][512];     // 8 KB per-wave transpose scratch

  const int tid  = threadIdx.x;
  const int lane = tid & 63;
  const int wv   = tid >> 6;
  const int lc   = lane & 15;
  const int q4   = lane >> 4;
  const int bb   = blockIdx.x >> 8;
  const int lb   = blockIdx.x & 255;

  const unsigned short* WoB = wbf + 4 * 16384;
  const unsigned short* Qs  = ws + WS_Q   + ((size_t)(bb * 256 + lb)) * SLICE;
  const unsigned short* Ks  = ws + WS_K   + ((size_t)(bb * 256 + lb)) * SLICE;
  const unsigned short* Vs  = ws + WS_V2T + ((size_t)(bb * 256 + lb)) * SLICE;
  const float* V1s = v1f + ((size_t)(bb * 256 + lb)) * 32768;

  const f32x4 Z4 = {0.f, 0.f, 0.f, 0.f};

  // stage pre-swizzled K slice -> LDS (linear copy)
  #pragma unroll 1
  for (int t = 0; t < 8; ++t) {
    const int idx = t * 512 + tid;
    *(f32x4*)(Kb + idx * 8) = *(const f32x4*)(Ks + idx * 8);
  }
  __syncthreads();

  unsigned short* chw = chunk[wv];

  #pragma unroll 1
  for (int half = 0; half < 2; ++half) {
    const int i0 = (wv + half * 8) * 16;

    // Q A-frags straight from global (pre-scaled, bias folded)
    bf16x8 aQ[4];
    #pragma unroll
    for (int kc = 0; kc < 4; ++kc)
      aQ[kc] = *(const bf16x8*)(Qs + (i0 + lc) * 128 + kc * 32 + q4 * 8);

    // S = Q K^T : 16 j-tiles of C-frags
    f32x4 S[16];
    #pragma unroll
    for (int jt = 0; jt < 16; ++jt) S[jt] = Z4;
    #pragma unroll 1
    for (int kc = 0; kc < 4; ++kc) {
      #pragma unroll
      for (int jt = 0; jt < 16; ++jt) {
        const int j = jt * 16 + lc;
        bf16x8 bK = *(const bf16x8*)(Kb + j * 128 + (((kc * 4 + q4) ^ lc) << 3));
        S[jt] = MFMA(aQ[kc], bK, S[jt]);
      }
    }

    // softmax over j; denominator deferred (inv[r])
    float inv[4];
    #pragma unroll
    for (int r = 0; r < 4; ++r) {
      float mx = -1e30f;
      #pragma unroll
      for (int jt = 0; jt < 16; ++jt) mx = fmaxf(mx, S[jt][r]);
      mx = fmaxf(mx, __shfl_xor(mx, 1));
      mx = fmaxf(mx, __shfl_xor(mx, 2));
      mx = fmaxf(mx, __shfl_xor(mx, 4));
      mx = fmaxf(mx, __shfl_xor(mx, 8));
      float sm = 0.f;
      #pragma unroll
      for (int jt = 0; jt < 16; ++jt) {
        float e = __expf(S[jt][r] - mx);
        S[jt][r] = e;
        sm += e;
      }
      sm += __shfl_xor(sm, 1);
      sm += __shfl_xor(sm, 2);
      sm += __shfl_xor(sm, 4);
      sm += __shfl_xor(sm, 8);
      inv[r] = 1.0f / sm;
    }

    // P -> bf16 A-frags via chunk transpose (frees S)
    bf16x8 aP[8];
    #pragma unroll 1
    for (int kc = 0; kc < 8; ++kc) {
      #pragma unroll
      for (int h = 0; h < 2; ++h) {
        const int jt = kc * 2 + h;
        #pragma unroll
        for (int r = 0; r < 4; ++r) {
          const int k = h * 16 + lc;
          const int m = q4 * 4 + r;
          chw[((m + ((k >> 3) << 4)) << 3) + (k & 7)] = rne_bf16(S[jt][r]);
        }
      }
      aP[kc] = *(const bf16x8*)(chw + lane * 8);
    }

    // ctx_raw = P @ V2 (B-frags from global V2T slice, L2/L3-hot)
    f32x4 Cx[8];
    #pragma unroll
    for (int n = 0; n < 8; ++n) Cx[n] = Z4;
    #pragma unroll 1
    for (int kc = 0; kc < 8; ++kc) {
      #pragma unroll
      for (int n = 0; n < 8; ++n) {
        bf16x8 bV = *(const bf16x8*)(Vs + (n * 16 + lc) * 256 + kc * 32 + q4 * 8);
        Cx[n] = MFMA(aP[kc], bV, Cx[n]);
      }
    }

    // Cx *= inv * V1 (V1 f32 from global, C-layout addressed)
    #pragma unroll
    for (int n = 0; n < 8; ++n) {
      #pragma unroll
      for (int r = 0; r < 4; ++r) {
        const float v1 = V1s[(i0 + q4 * 4 + r) * 128 + n * 16 + lc];
        Cx[n][r] *= inv[r] * v1;
      }
    }

    // out = ctx @ Wo^T + bo
    bf16x8 aC[4];
    #pragma unroll 1
    for (int kc = 0; kc < 4; ++kc) {
      #pragma unroll
      for (int h = 0; h < 2; ++h) {
        const int nt = kc * 2 + h;
        #pragma unroll
        for (int r = 0; r < 4; ++r) {
          const int k = h * 16 + lc;
          const int m = q4 * 4 + r;
          chw[((m + ((k >> 3) << 4)) << 3) + (k & 7)] = rne_bf16(Cx[nt][r]);
        }
      }
      aC[kc] = *(const bf16x8*)(chw + lane * 8);
    }
    f32x4 O[8];
    #pragma unroll
    for (int n = 0; n < 8; ++n) O[n] = Z4;
    #pragma unroll 1
    for (int kc = 0; kc < 4; ++kc) {
      #pragma unroll
      for (int n = 0; n < 8; ++n) {
        bf16x8 bw = *(const bf16x8*)(WoB + (n * 16 + lc) * 128 + kc * 32 + q4 * 8);
        O[n] = MFMA(aC[kc], bw, O[n]);
      }
    }
    #pragma unroll
    for (int n = 0; n < 8; ++n) {
      const float bov = bo[n * 16 + lc];
      #pragma unroll
      for (int r = 0; r < 4; ++r) {
        const int i = i0 + q4 * 4 + r;
        out[(((size_t)(bb * 256 + i)) * 256 + lb) * 128 + n * 16 + lc] = O[n][r] + bov;
      }
    }
  }
}

// ---------------------------------------------------------------------------
// Fallback: round-1 fused kernel (used when workspace too small).
// ---------------------------------------------------------------------------
__global__ __launch_bounds__(1024, 4)
void edge_attn_fused(const float* __restrict__ ef,
                     const unsigned short* __restrict__ wbf,
                     const float* __restrict__ bq, const float* __restrict__ bk,
                     const float* __restrict__ bv1, const float* __restrict__ bv2,
                     const float* __restrict__ bo,
                     float* __restrict__ out) {
  __shared__ unsigned short Kb[256 * 128];
  __shared__ unsigned short V2t[128 * 256];
  __shared__ unsigned short chunk[16][512];

  const int tid  = threadIdx.x;
  const int lane = tid & 63;
  const int wv   = tid >> 6;
  const int lc   = lane & 15;
  const int q4   = lane >> 4;
  const int bb   = blockIdx.x >> 8;
  const int lb   = blockIdx.x & 255;

  const unsigned short* WqB  = wbf;
  const unsigned short* WkB  = wbf + 16384;
  const unsigned short* Wv1B = wbf + 2 * 16384;
  const unsigned short* Wv2B = wbf + 3 * 16384;
  const unsigned short* WoB  = wbf + 4 * 16384;
  const f32x4 Z4 = {0.f, 0.f, 0.f, 0.f};

  {
    const float* Frow = ef + ((size_t)(bb * 256 + lb)) * (256 * 128);
    const int j0 = wv * 16;
    bf16x8 aF[4];
    const float* rp = Frow + (j0 + lc) * 128 + q4 * 8;
    #pragma unroll
    for (int kc = 0; kc < 4; ++kc) aF[kc] = cvt_frag(rp + kc * 32);
    f32x4 accK[8], accV[8];
    #pragma unroll
    for (int n = 0; n < 8; ++n) { accK[n] = Z4; accV[n] = Z4; }
    #pragma unroll
    for (int kc = 0; kc < 4; ++kc) {
      #pragma unroll
      for (int n = 0; n < 8; ++n) {
        bf16x8 bwk = *(const bf16x8*)(WkB  + (n * 16 + lc) * 128 + kc * 32 + q4 * 8);
        bf16x8 bwv = *(const bf16x8*)(Wv2B + (n * 16 + lc) * 128 + kc * 32 + q4 * 8);
        accK[n] = MFMA(aF[kc], bwk, accK[n]);
        accV[n] = MFMA(aF[kc], bwv, accV[n]);
      }
    }
    #pragma unroll
    for (int n = 0; n < 8; ++n) {
      const int o = n * 16 + lc;
      const float bkv = bk[o];
      const float bvv = bv2[o];
      #pragma unroll
      for (int r = 0; r < 4; ++r) {
        const int j = j0 + q4 * 4 + r;
        Kb[j * 128 + (((o >> 3) ^ (j & 15)) << 3) + (o & 7)] = rne_bf16(accK[n][r] + bkv);
        V2t[o * 256 + (((j >> 3) ^ lc) << 3) + (j & 7)]      = rne_bf16(accV[n][r] + bvv);
      }
    }
  }
  __syncthreads();

  const float scale = 0.08838834764831845f;
  unsigned short* chw = chunk[wv];
  const int i0 = wv * 16;

  bf16x8 aE[4];
  {
    const float* rp = ef + (((size_t)(bb * 256 + i0 + lc)) * 256 + lb) * 128 + q4 * 8;
    #pragma unroll
    for (int kc = 0; kc < 4; ++kc) aE[kc] = cvt_frag(rp + kc * 32);
  }
  f32x4 Qf[8];
  #pragma unroll
  for (int n = 0; n < 8; ++n) Qf[n] = Z4;
  #pragma unroll
  for (int kc = 0; kc < 4; ++kc) {
    #pragma unroll
    for (int n = 0; n < 8; ++n) {
      bf16x8 bwq = *(const bf16x8*)(WqB + (n * 16 + lc) * 128 + kc * 32 + q4 * 8);
      Qf[n] = MFMA(aE[kc], bwq, Qf[n]);
    }
  }
  bf16x8 aQ[4];
  #pragma unroll
  for (int kc = 0; kc < 4; ++kc) {
    #pragma unroll
    for (int h = 0; h < 2; ++h) {
      const int nt = kc * 2 + h;
      const float bqv = bq[nt * 16 + lc];
      #pragma unroll
      for (int r = 0; r < 4; ++r) {
        const int k = h * 16 + lc;
        const int m = q4 * 4 + r;
        chw[((m + ((k >> 3) << 4)) << 3) + (k & 7)] = rne_bf16((Qf[nt][r] + bqv) * scale);
      }
    }
    aQ[kc] = *(const bf16x8*)(chw + lane * 8);
  }
  f32x4 S[16];
  #pragma unroll
  for (int jt = 0; jt < 16; ++jt) S[jt] = Z4;
  #pragma unroll
  for (int kc = 0; kc < 4; ++kc) {
    #pragma unroll
    for (int jt = 0; jt < 16; ++jt) {
      const int j = jt * 16 + lc;
      bf16x8 bK = *(const bf16x8*)(Kb + j * 128 + (((kc * 4 + q4) ^ lc) << 3));
      S[jt] = MFMA(aQ[kc], bK, S[jt]);
    }
  }
  float inv[4];
  #pragma unroll
  for (int r = 0; r < 4; ++r) {
    float mx = -1e30f;
    #pragma unroll
    for (int jt = 0; jt < 16; ++jt) mx = fmaxf(mx, S[jt][r]);
    mx = fmaxf(mx, __shfl_xor(mx, 1));
    mx = fmaxf(mx, __shfl_xor(mx, 2));
    mx = fmaxf(mx, __shfl_xor(mx, 4));
    mx = fmaxf(mx, __shfl_xor(mx, 8));
    float sm = 0.f;
    #pragma unroll
    for (int jt = 0; jt < 16; ++jt) {
      float e = __expf(S[jt][r] - mx);
      S[jt][r] = e;
      sm += e;
    }
    sm += __shfl_xor(sm, 1);
    sm += __shfl_xor(sm, 2);
    sm += __shfl_xor(sm, 4);
    sm += __shfl_xor(sm, 8);
    inv[r] = 1.0f / sm;
  }
  bf16x8 aP[8];
  #pragma unroll
  for (int kc = 0; kc < 8; ++kc) {
    #pragma unroll
    for (int h = 0; h < 2; ++h) {
      const int jt = kc * 2 + h;
      #pragma unroll
      for (int r = 0; r < 4; ++r) {
        const int k = h * 16 + lc;
        const int m = q4 * 4 + r;
        chw[((m + ((k >> 3) << 4)) << 3) + (k & 7)] = rne_bf16(S[jt][r]);
      }
    }
    aP[kc] = *(const bf16x8*)(chw + lane * 8);
  }
  f32x4 Cx[8];
  #pragma unroll
  for (int n = 0; n < 8; ++n) Cx[n] = Z4;
  #pragma unroll
  for (int kc = 0; kc < 8; ++kc) {
    #pragma unroll
    for (int n = 0; n < 8; ++n) {
      const int d = n * 16 + lc;
      bf16x8 bV = *(const bf16x8*)(V2t + d * 256 + (((kc * 4 + q4) ^ lc) << 3));
      Cx[n] = MFMA(aP[kc], bV, Cx[n]);
    }
  }
  f32x4 V1f[8];
  #pragma unroll
  for (int n = 0; n < 8; ++n) V1f[n] = Z4;
  #pragma unroll
  for (int kc = 0; kc < 4; ++kc) {
    #pragma unroll
    for (int n = 0; n < 8; ++n) {
      bf16x8 bwv = *(const bf16x8*)(Wv1B + (n * 16 + lc) * 128 + kc * 32 + q4 * 8);
      V1f[n] = MFMA(aE[kc], bwv, V1f[n]);
    }
  }
  #pragma unroll
  for (int n = 0; n < 8; ++n) {
    const float bvv = bv1[n * 16 + lc];
    #pragma unroll
    for (int r = 0; r < 4; ++r) Cx[n][r] *= inv[r] * (V1f[n][r] + bvv);
  }
  bf16x8 aC[4];
  #pragma unroll
  for (int kc = 0; kc < 4; ++kc) {
    #pragma unroll
    for (int h = 0; h < 2; ++h) {
      const int nt = kc * 2 + h;
      #pragma unroll
      for (int r = 0; r < 4; ++r) {
        const int k = h * 16 + lc;
        const int m = q4 * 4 + r;
        chw[((m + ((k >> 3) << 4)) << 3) + (k & 7)] = rne_bf16(Cx[nt][r]);
      }
    }
    aC[kc] = *(const bf16x8*)(chw + lane * 8);
  }
  f32x4 O[8];
  #pragma unroll
  for (int n = 0; n < 8; ++n) O[n] = Z4;
  #pragma unroll
  for (int kc = 0; kc < 4; ++kc) {
    #pragma unroll
    for (int n = 0; n < 8; ++n) {
      bf16x8 bw = *(const bf16x8*)(WoB + (n * 16 + lc) * 128 + kc * 32 + q4 * 8);
      O[n] = MFMA(aC[kc], bw, O[n]);
    }
  }
  #pragma unroll
  for (int n = 0; n < 8; ++n) {
    const float bov = bo[n * 16 + lc];
    #pragma unroll
    for (int r = 0; r < 4; ++r) {
      const int i = i0 + q4 * 4 + r;
      out[(((size_t)(bb * 256 + i)) * 256 + lb) * 128 + n * 16 + lc] = O[n][r] + bov;
    }
  }
}

extern "C" void kernel_launch(void* const* d_in, const int* in_sizes, int n_in,
                              void* d_out, int out_size, void* d_ws, size_t ws_size,
                              hipStream_t stream) {
  const float* ef   = (const float*)d_in[0];
  const float* Wq   = (const float*)d_in[1];
  const float* bqp  = (const float*)d_in[2];
  const float* Wk   = (const float*)d_in[3];
  const float* bkp  = (const float*)d_in[4];
  const float* Wv1  = (const float*)d_in[5];
  const float* bv1p = (const float*)d_in[6];
  const float* Wv2  = (const float*)d_in[7];
  const float* bv2p = (const float*)d_in[8];
  const float* Wo   = (const float*)d_in[9];
  const float* bop  = (const float*)d_in[10];
  unsigned short* wbf = (unsigned short*)d_ws;

  cvt_weights<<<64, 256, 0, stream>>>(Wq, Wk, Wv1, Wv2, Wo, wbf);

  if (ws_size >= WS_NEEDED) {
    float* v1f = (float*)((char*)d_ws + WS_V1_B);
    proj_kernel<<<512, 512, 0, stream>>>(ef, wbf, bqp, bkp, bv1p, bv2p, wbf, v1f);
    attn_kernel<<<512, 512, 0, stream>>>(wbf, bop, wbf, v1f, (float*)d_out);
  } else {
    edge_attn_fused<<<512, 1024, 0, stream>>>(ef, wbf, bqp, bkp, bv1p, bv2p, bop,
                                              (float*)d_out);
  }
}

// Round 3
// 320.278 us; speedup vs baseline: 1.7578x; 1.7578x over previous
//
#include <hip/hip_runtime.h>

// EdgeAttention fused kernel for MI355X (gfx950) — round 3.
// One workgroup (1024 thr = 16 waves) per (b,l). Phase 1: K/V2 projected into
// LDS (bf16, swizzled). Phase 2 (per-wave 16-row i-tile), all-register flow:
//   Q^T = mfma(Wq, E)            (o on q4-axis, i on lanes)
//   bQ  = cvt_pk + ds_bpermute transpose (register-only)
//   S^T = mfma(K, bQ)            -> softmax over j is LANE-LOCAL (i = lc)
//   aP  = cvt_pk + bpermute transpose of normalized P
//   Ct  = mfma(V2^T, aP)         (d on q4-axis, i on lanes)
//   V1^T= mfma(Wv1, E); Ct *= (V1^T + bv1)
//   aC  = cvt_pk + bpermute transpose
//   O   = mfma(aC, Wo) + bo      (C-layout, coalesced store)
// No LDS chunk round-trips; phase-2 E rows prefetched before the barrier so the
// strided gather latency is absorbed by the barrier wait.
// MFMA layouts (m89/m91/m120-verified):
//   A/B-frag: elem[j] = X[row = lane&15][k = (lane>>4)*8 + j]
//   C/D     : c[r] = D[m = (lane>>4)*4 + r][n = lane&15]
//   (m-axis indexes the FIRST operand's rows, n-axis the second's.)

typedef __bf16 bf16x8 __attribute__((ext_vector_type(8)));
typedef float  f32x4  __attribute__((ext_vector_type(4)));

#define MFMA(a, b, c) __builtin_amdgcn_mfma_f32_16x16x32_bf16((a), (b), (c), 0, 0, 0)

union U8 { bf16x8 v; unsigned int w[4]; };

__device__ __forceinline__ unsigned short rne_bf16(float f) {
  unsigned int u = __float_as_uint(f);
  u += 0x7fffu + ((u >> 16) & 1u);   // round-to-nearest-even
  return (unsigned short)(u >> 16);
}

// packed f32x2 -> bf16x2 (RNE), single instruction
__device__ __forceinline__ unsigned int cvt_pk(float lo, float hi) {
  unsigned int r;
  asm("v_cvt_pk_bf16_f32 %0, %1, %2" : "=v"(r) : "v"(lo), "v"(hi));
  return r;
}

// load 8 consecutive fp32 (16B aligned) and convert to a bf16x8 fragment
__device__ __forceinline__ bf16x8 cvt_frag(const float* __restrict__ p) {
  f32x4 a = *(const f32x4*)p;
  f32x4 b = *(const f32x4*)(p + 4);
  U8 t;
  t.w[0] = cvt_pk(a[0], a[1]);
  t.w[1] = cvt_pk(a[2], a[3]);
  t.w[2] = cvt_pk(b[0], b[1]);
  t.w[3] = cvt_pk(b[2], b[3]);
  return t.v;
}

// Setup: convert the 5 weight matrices fp32 -> bf16 into d_ws.
__global__ void cvt_weights(const float* __restrict__ Wq, const float* __restrict__ Wk,
                            const float* __restrict__ Wv1, const float* __restrict__ Wv2,
                            const float* __restrict__ Wo, unsigned short* __restrict__ ws) {
  int t = blockIdx.x * 256 + threadIdx.x;   // 0..16383
  ws[t]             = rne_bf16(Wq[t]);
  ws[16384 + t]     = rne_bf16(Wk[t]);
  ws[2 * 16384 + t] = rne_bf16(Wv1[t]);
  ws[3 * 16384 + t] = rne_bf16(Wv2[t]);
  ws[4 * 16384 + t] = rne_bf16(Wo[t]);
}

__global__ __launch_bounds__(1024, 4)
void edge_attn_kernel(const float* __restrict__ ef,
                      const unsigned short* __restrict__ wbf,
                      const float* __restrict__ bq, const float* __restrict__ bk,
                      const float* __restrict__ bv1, const float* __restrict__ bv2,
                      const float* __restrict__ bo,
                      float* __restrict__ out) {
  // K rows (j-major) swizzled: elem (j,o) at j*128 + (((o>>3) ^ (j&15))<<3) + (o&7)
  __shared__ unsigned short Kb[256 * 128];
  // V2 transposed (d-major) swizzled: elem (j,d) at d*256 + (((j>>3) ^ (d&15))<<3) + (j&7)
  __shared__ unsigned short V2t[128 * 256];

  const int tid  = threadIdx.x;
  const int lane = tid & 63;
  const int wv   = tid >> 6;    // wave 0..15
  const int lc   = lane & 15;
  const int q4   = lane >> 4;
  const int bb   = blockIdx.x >> 8;
  const int lb   = blockIdx.x & 255;

  const unsigned short* WqB  = wbf;
  const unsigned short* WkB  = wbf + 16384;
  const unsigned short* Wv1B = wbf + 2 * 16384;
  const unsigned short* Wv2B = wbf + 3 * 16384;
  const unsigned short* WoB  = wbf + 4 * 16384;

  const f32x4 Z4 = {0.f, 0.f, 0.f, 0.f};
  const int i0 = wv * 16;

  // ---------------- Phase 1: K = F@Wk^T + bk, V2 = F@Wv2^T + bv2 into LDS ---
  {
    const float* Frow = ef + ((size_t)(bb * 256 + lb)) * (256 * 128);
    const int j0 = wv * 16;
    bf16x8 aF[4];
    const float* rp = Frow + (j0 + lc) * 128 + q4 * 8;
    #pragma unroll
    for (int kc = 0; kc < 4; ++kc) aF[kc] = cvt_frag(rp + kc * 32);

    f32x4 accK[8], accV[8];
    #pragma unroll
    for (int n = 0; n < 8; ++n) { accK[n] = Z4; accV[n] = Z4; }
    #pragma unroll
    for (int kc = 0; kc < 4; ++kc) {
      #pragma unroll
      for (int n = 0; n < 8; ++n) {
        bf16x8 bwk = *(const bf16x8*)(WkB  + (n * 16 + lc) * 128 + kc * 32 + q4 * 8);
        bf16x8 bwv = *(const bf16x8*)(Wv2B + (n * 16 + lc) * 128 + kc * 32 + q4 * 8);
        accK[n] = MFMA(aF[kc], bwk, accK[n]);
        accV[n] = MFMA(aF[kc], bwv, accV[n]);
      }
    }
    #pragma unroll
    for (int n = 0; n < 8; ++n) {
      const int o = n * 16 + lc;
      const float bkv = bk[o];
      const float bvv = bv2[o];
      #pragma unroll
      for (int r = 0; r < 4; ++r) {
        const int j = j0 + q4 * 4 + r;
        Kb[j * 128 + (((o >> 3) ^ (j & 15)) << 3) + (o & 7)] = rne_bf16(accK[n][r] + bkv);
        V2t[o * 256 + (((j >> 3) ^ lc) << 3) + (j & 7)]      = rne_bf16(accV[n][r] + bvv);
      }
    }
  }

  // Prefetch phase-2 E rows (strided gather). Issued before the barrier so the
  // compiler's vmcnt drain at __syncthreads overlaps this latency with the
  // barrier wait instead of exposing it at the head of phase 2.
  f32x4 eE[8];
  {
    const float* rpE = ef + (((size_t)(bb * 256 + i0 + lc)) * 256 + lb) * 128 + q4 * 8;
    #pragma unroll
    for (int kc = 0; kc < 4; ++kc) {
      eE[2 * kc]     = *(const f32x4*)(rpE + kc * 32);
      eE[2 * kc + 1] = *(const f32x4*)(rpE + kc * 32 + 4);
    }
  }
  __syncthreads();

  // ---------------- Phase 2: per-wave i-tile attention ----------------------
  const float scale = 0.08838834764831845f;  // 1/sqrt(128)

  // E-row fragments (B operand for Q^T/V1^T projections)
  bf16x8 aE[4];
  #pragma unroll
  for (int kc = 0; kc < 4; ++kc) {
    U8 u;
    u.w[0] = cvt_pk(eE[2 * kc][0], eE[2 * kc][1]);
    u.w[1] = cvt_pk(eE[2 * kc][2], eE[2 * kc][3]);
    u.w[2] = cvt_pk(eE[2 * kc + 1][0], eE[2 * kc + 1][1]);
    u.w[3] = cvt_pk(eE[2 * kc + 1][2], eE[2 * kc + 1][3]);
    aE[kc] = u.v;
  }

  // Q^T projection: Qt[nt] c[r] = Q[i=lc][o = nt*16 + q4*4 + r]
  f32x4 Qt[8];
  #pragma unroll
  for (int nt = 0; nt < 8; ++nt) Qt[nt] = Z4;
  #pragma unroll
  for (int kc = 0; kc < 4; ++kc) {
    #pragma unroll
    for (int nt = 0; nt < 8; ++nt) {
      bf16x8 aW = *(const bf16x8*)(WqB + (nt * 16 + lc) * 128 + kc * 32 + q4 * 8);
      Qt[nt] = MFMA(aW, aE[kc], Qt[nt]);
    }
  }
  // bias + scale, pack to bf16 pairs (pair = adjacent o)
  unsigned int q01[8], q23[8];
  #pragma unroll
  for (int nt = 0; nt < 8; ++nt) {
    f32x4 b4 = *(const f32x4*)(bq + nt * 16 + q4 * 4);
    q01[nt] = cvt_pk((Qt[nt][0] + b4[0]) * scale, (Qt[nt][1] + b4[1]) * scale);
    q23[nt] = cvt_pk((Qt[nt][2] + b4[2]) * scale, (Qt[nt][3] + b4[3]) * scale);
  }

  // cross-q4 transpose sources (i stays on lc; only the q4 group changes)
  const int sa = ((2 * q4) & 3) * 16 + lc;       // source lane for elems 0..3
  const int sb = ((2 * q4 + 1) & 3) * 16 + lc;   // source lane for elems 4..7
  const bool hi = (q4 >= 2);                     // selects odd source tile

  // bQ[kc] elem[kk] = Q[i=lc][d = kc*32 + q4*8 + kk]
  bf16x8 bQ[4];
  #pragma unroll
  for (int kc = 0; kc < 4; ++kc) {
    U8 u;
    { int x0 = __shfl((int)q01[2 * kc], sa), x1 = __shfl((int)q01[2 * kc + 1], sa);
      u.w[0] = (unsigned int)(hi ? x1 : x0); }
    { int x0 = __shfl((int)q23[2 * kc], sa), x1 = __shfl((int)q23[2 * kc + 1], sa);
      u.w[1] = (unsigned int)(hi ? x1 : x0); }
    { int x0 = __shfl((int)q01[2 * kc], sb), x1 = __shfl((int)q01[2 * kc + 1], sb);
      u.w[2] = (unsigned int)(hi ? x1 : x0); }
    { int x0 = __shfl((int)q23[2 * kc], sb), x1 = __shfl((int)q23[2 * kc + 1], sb);
      u.w[3] = (unsigned int)(hi ? x1 : x0); }
    bQ[kc] = u.v;
  }

  // S^T = mfma(K, Q): ST[jt] c[r] = S^T[j = jt*16+q4*4+r][i = i0+lc]
  f32x4 ST[16];
  #pragma unroll
  for (int jt = 0; jt < 16; ++jt) ST[jt] = Z4;
  #pragma unroll
  for (int kc = 0; kc < 4; ++kc) {
    #pragma unroll
    for (int jt = 0; jt < 16; ++jt) {
      bf16x8 bK = *(const bf16x8*)(Kb + (jt * 16 + lc) * 128 + (((kc * 4 + q4) ^ lc) << 3));
      ST[jt] = MFMA(bK, bQ[kc], ST[jt]);
    }
  }

  // softmax over j: lane-local 64 values + cross-q4 shfl_xor reduce
  float t16[16];
  #pragma unroll
  for (int jt = 0; jt < 16; ++jt)
    t16[jt] = fmaxf(fmaxf(ST[jt][0], ST[jt][1]), fmaxf(ST[jt][2], ST[jt][3]));
  #pragma unroll
  for (int s = 8; s >= 1; s >>= 1)
    #pragma unroll
    for (int k = 0; k < 16 && k < s; ++k) t16[k] = fmaxf(t16[k], t16[k + s]);
  float mx = t16[0];
  mx = fmaxf(mx, __shfl_xor(mx, 16));
  mx = fmaxf(mx, __shfl_xor(mx, 32));

  float s16[16];
  #pragma unroll
  for (int jt = 0; jt < 16; ++jt) {
    float e0 = __expf(ST[jt][0] - mx);
    float e1 = __expf(ST[jt][1] - mx);
    float e2 = __expf(ST[jt][2] - mx);
    float e3 = __expf(ST[jt][3] - mx);
    ST[jt][0] = e0; ST[jt][1] = e1; ST[jt][2] = e2; ST[jt][3] = e3;
    s16[jt] = (e0 + e1) + (e2 + e3);
  }
  #pragma unroll
  for (int s = 8; s >= 1; s >>= 1)
    #pragma unroll
    for (int k = 0; k < 16 && k < s; ++k) s16[k] += s16[k + s];
  float sm = s16[0];
  sm += __shfl_xor(sm, 16);
  sm += __shfl_xor(sm, 32);
  const float inv = 1.0f / sm;

  // normalized P -> bf16 pairs (pair = adjacent j)
  unsigned int p01[16], p23[16];
  #pragma unroll
  for (int jt = 0; jt < 16; ++jt) {
    p01[jt] = cvt_pk(ST[jt][0] * inv, ST[jt][1] * inv);
    p23[jt] = cvt_pk(ST[jt][2] * inv, ST[jt][3] * inv);
  }

  // aP[kc] elem[kk] = P[i=lc][j = kc*32 + q4*8 + kk]
  bf16x8 aP[8];
  #pragma unroll
  for (int kc = 0; kc < 8; ++kc) {
    U8 u;
    { int x0 = __shfl((int)p01[2 * kc], sa), x1 = __shfl((int)p01[2 * kc + 1], sa);
      u.w[0] = (unsigned int)(hi ? x1 : x0); }
    { int x0 = __shfl((int)p23[2 * kc], sa), x1 = __shfl((int)p23[2 * kc + 1], sa);
      u.w[1] = (unsigned int)(hi ? x1 : x0); }
    { int x0 = __shfl((int)p01[2 * kc], sb), x1 = __shfl((int)p01[2 * kc + 1], sb);
      u.w[2] = (unsigned int)(hi ? x1 : x0); }
    { int x0 = __shfl((int)p23[2 * kc], sb), x1 = __shfl((int)p23[2 * kc + 1], sb);
      u.w[3] = (unsigned int)(hi ? x1 : x0); }
    aP[kc] = u.v;
  }

  // Ct = mfma(V2^T, P): Ct[nt] c[r] = ctx[i=lc][d = nt*16+q4*4+r]
  f32x4 Ct[8];
  #pragma unroll
  for (int nt = 0; nt < 8; ++nt) Ct[nt] = Z4;
  #pragma unroll
  for (int kc = 0; kc < 8; ++kc) {
    #pragma unroll
    for (int nt = 0; nt < 8; ++nt) {
      bf16x8 bV = *(const bf16x8*)(V2t + (nt * 16 + lc) * 256 + (((kc * 4 + q4) ^ lc) << 3));
      Ct[nt] = MFMA(bV, aP[kc], Ct[nt]);
    }
  }

  // V1^T projection, then Ct *= (V1^T + bv1)   (same layout: d on q4-axis)
  f32x4 Vt[8];
  #pragma unroll
  for (int nt = 0; nt < 8; ++nt) Vt[nt] = Z4;
  #pragma unroll
  for (int kc = 0; kc < 4; ++kc) {
    #pragma unroll
    for (int nt = 0; nt < 8; ++nt) {
      bf16x8 aW = *(const bf16x8*)(Wv1B + (nt * 16 + lc) * 128 + kc * 32 + q4 * 8);
      Vt[nt] = MFMA(aW, aE[kc], Vt[nt]);
    }
  }
  #pragma unroll
  for (int nt = 0; nt < 8; ++nt) {
    f32x4 b4 = *(const f32x4*)(bv1 + nt * 16 + q4 * 4);
    #pragma unroll
    for (int r = 0; r < 4; ++r) Ct[nt][r] *= (Vt[nt][r] + b4[r]);
  }

  // pack ctx pairs (pair = adjacent d)
  unsigned int c01[8], c23[8];
  #pragma unroll
  for (int nt = 0; nt < 8; ++nt) {
    c01[nt] = cvt_pk(Ct[nt][0], Ct[nt][1]);
    c23[nt] = cvt_pk(Ct[nt][2], Ct[nt][3]);
  }

  // aC[kc] elem[kk] = ctx[i=lc][d = kc*32 + q4*8 + kk]
  bf16x8 aC[4];
  #pragma unroll
  for (int kc = 0; kc < 4; ++kc) {
    U8 u;
    { int x0 = __shfl((int)c01[2 * kc], sa), x1 = __shfl((int)c01[2 * kc + 1], sa);
      u.w[0] = (unsigned int)(hi ? x1 : x0); }
    { int x0 = __shfl((int)c23[2 * kc], sa), x1 = __shfl((int)c23[2 * kc + 1], sa);
      u.w[1] = (unsigned int)(hi ? x1 : x0); }
    { int x0 = __shfl((int)c01[2 * kc], sb), x1 = __shfl((int)c01[2 * kc + 1], sb);
      u.w[2] = (unsigned int)(hi ? x1 : x0); }
    { int x0 = __shfl((int)c23[2 * kc], sb), x1 = __shfl((int)c23[2 * kc + 1], sb);
      u.w[3] = (unsigned int)(hi ? x1 : x0); }
    aC[kc] = u.v;
  }

  // O = ctx @ Wo^T + bo (normal orientation -> C-layout, coalesced store)
  f32x4 O[8];
  #pragma unroll
  for (int n = 0; n < 8; ++n) O[n] = Z4;
  #pragma unroll
  for (int kc = 0; kc < 4; ++kc) {
    #pragma unroll
    for (int n = 0; n < 8; ++n) {
      bf16x8 bw = *(const bf16x8*)(WoB + (n * 16 + lc) * 128 + kc * 32 + q4 * 8);
      O[n] = MFMA(aC[kc], bw, O[n]);
    }
  }
  #pragma unroll
  for (int n = 0; n < 8; ++n) {
    const float bov = bo[n * 16 + lc];
    #pragma unroll
    for (int r = 0; r < 4; ++r) {
      const int i = i0 + q4 * 4 + r;
      out[(((size_t)(bb * 256 + i)) * 256 + lb) * 128 + n * 16 + lc] = O[n][r] + bov;
    }
  }
}

extern "C" void kernel_launch(void* const* d_in, const int* in_sizes, int n_in,
                              void* d_out, int out_size, void* d_ws, size_t ws_size,
                              hipStream_t stream) {
  const float* ef   = (const float*)d_in[0];
  const float* Wq   = (const float*)d_in[1];
  const float* bqp  = (const float*)d_in[2];
  const float* Wk   = (const float*)d_in[3];
  const float* bkp  = (const float*)d_in[4];
  const float* Wv1  = (const float*)d_in[5];
  const float* bv1p = (const float*)d_in[6];
  const float* Wv2  = (const float*)d_in[7];
  const float* bv2p = (const float*)d_in[8];
  const float* Wo   = (const float*)d_in[9];
  const float* bop  = (const float*)d_in[10];
  unsigned short* wbf = (unsigned short*)d_ws;   // 5 * 128*128 bf16 = 160 KB

  cvt_weights<<<64, 256, 0, stream>>>(Wq, Wk, Wv1, Wv2, Wo, wbf);
  edge_attn_kernel<<<512, 1024, 0, stream>>>(ef, wbf, bqp, bkp, bv1p, bv2p, bop,
                                             (float*)d_out);
}

// Round 4
// 235.412 us; speedup vs baseline: 2.3915x; 1.3605x over previous
//
#include <hip/hip_runtime.h>

// EdgeAttention fused kernel for MI355X (gfx950) — round 4.
// One workgroup (512 thr = 8 waves) per (b,l); 256-reg budget (launch_bounds 512,2).
// Each wave owns TWO 16-row i-tiles (A: wv*16, B: wv*16+128) processed in
// lockstep so every shared operand load (phase-1 weight frags, Wq/Wv1/Wo frags,
// K and V2 LDS reads) feeds two MFMAs, and tile-B MFMA overlaps tile-A softmax
// VALU. Register flow identical to round 3 per tile (shuffle transposes, no
// chunk LDS). MFMA layouts (m89/m91/m120-verified):
//   A/B-frag: elem[j] = X[row = lane&15][k = (lane>>4)*8 + j]
//   C/D     : c[r] = D[m = (lane>>4)*4 + r][n = lane&15]

typedef __bf16 bf16x8 __attribute__((ext_vector_type(8)));
typedef float  f32x4  __attribute__((ext_vector_type(4)));

#define MFMA(a, b, c) __builtin_amdgcn_mfma_f32_16x16x32_bf16((a), (b), (c), 0, 0, 0)

union U8 { bf16x8 v; unsigned int w[4]; };

__device__ __forceinline__ unsigned short rne_bf16(float f) {
  unsigned int u = __float_as_uint(f);
  u += 0x7fffu + ((u >> 16) & 1u);   // round-to-nearest-even
  return (unsigned short)(u >> 16);
}

// packed f32x2 -> bf16x2 (RNE), single instruction
__device__ __forceinline__ unsigned int cvt_pk(float lo, float hi) {
  unsigned int r;
  asm("v_cvt_pk_bf16_f32 %0, %1, %2" : "=v"(r) : "v"(lo), "v"(hi));
  return r;
}

__device__ __forceinline__ bf16x8 cvt_frag(const float* __restrict__ p) {
  f32x4 a = *(const f32x4*)p;
  f32x4 b = *(const f32x4*)(p + 4);
  U8 t;
  t.w[0] = cvt_pk(a[0], a[1]);
  t.w[1] = cvt_pk(a[2], a[3]);
  t.w[2] = cvt_pk(b[0], b[1]);
  t.w[3] = cvt_pk(b[2], b[3]);
  return t.v;
}

// cross-q4 transpose step (verified round 3): builds one A/B-frag word set from
// packed C-layout pairs. w01a/w01b = x01[2kc]/x01[2kc+1], w23a/w23b likewise.
__device__ __forceinline__ bf16x8 xpose(unsigned int w01a, unsigned int w01b,
                                        unsigned int w23a, unsigned int w23b,
                                        int sa, int sb, bool hi) {
  U8 u;
  { int x0 = __shfl((int)w01a, sa), x1 = __shfl((int)w01b, sa);
    u.w[0] = (unsigned int)(hi ? x1 : x0); }
  { int x0 = __shfl((int)w23a, sa), x1 = __shfl((int)w23b, sa);
    u.w[1] = (unsigned int)(hi ? x1 : x0); }
  { int x0 = __shfl((int)w01a, sb), x1 = __shfl((int)w01b, sb);
    u.w[2] = (unsigned int)(hi ? x1 : x0); }
  { int x0 = __shfl((int)w23a, sb), x1 = __shfl((int)w23b, sb);
    u.w[3] = (unsigned int)(hi ? x1 : x0); }
  return u.v;
}

// lane-local softmax over j (verified round 3): ST holds S^T c-frags
// (j on q4-axis/regs, i on lc). Normalizes and packs into bf16 pair words.
__device__ __forceinline__ void softmax_pack(f32x4 ST[16], unsigned int p01[16],
                                             unsigned int p23[16]) {
  float t16[16];
  #pragma unroll
  for (int jt = 0; jt < 16; ++jt)
    t16[jt] = fmaxf(fmaxf(ST[jt][0], ST[jt][1]), fmaxf(ST[jt][2], ST[jt][3]));
  #pragma unroll
  for (int s = 8; s >= 1; s >>= 1)
    #pragma unroll
    for (int k = 0; k < 16; ++k) if (k < s) t16[k] = fmaxf(t16[k], t16[k + s]);
  float mx = t16[0];
  mx = fmaxf(mx, __shfl_xor(mx, 16));
  mx = fmaxf(mx, __shfl_xor(mx, 32));

  float s16[16];
  #pragma unroll
  for (int jt = 0; jt < 16; ++jt) {
    float e0 = __expf(ST[jt][0] - mx);
    float e1 = __expf(ST[jt][1] - mx);
    float e2 = __expf(ST[jt][2] - mx);
    float e3 = __expf(ST[jt][3] - mx);
    ST[jt][0] = e0; ST[jt][1] = e1; ST[jt][2] = e2; ST[jt][3] = e3;
    s16[jt] = (e0 + e1) + (e2 + e3);
  }
  #pragma unroll
  for (int s = 8; s >= 1; s >>= 1)
    #pragma unroll
    for (int k = 0; k < 16; ++k) if (k < s) s16[k] += s16[k + s];
  float sm = s16[0];
  sm += __shfl_xor(sm, 16);
  sm += __shfl_xor(sm, 32);
  const float inv = 1.0f / sm;

  #pragma unroll
  for (int jt = 0; jt < 16; ++jt) {
    p01[jt] = cvt_pk(ST[jt][0] * inv, ST[jt][1] * inv);
    p23[jt] = cvt_pk(ST[jt][2] * inv, ST[jt][3] * inv);
  }
}

// Setup: convert the 5 weight matrices fp32 -> bf16 into d_ws.
__global__ void cvt_weights(const float* __restrict__ Wq, const float* __restrict__ Wk,
                            const float* __restrict__ Wv1, const float* __restrict__ Wv2,
                            const float* __restrict__ Wo, unsigned short* __restrict__ ws) {
  int t = blockIdx.x * 256 + threadIdx.x;   // 0..16383
  ws[t]             = rne_bf16(Wq[t]);
  ws[16384 + t]     = rne_bf16(Wk[t]);
  ws[2 * 16384 + t] = rne_bf16(Wv1[t]);
  ws[3 * 16384 + t] = rne_bf16(Wv2[t]);
  ws[4 * 16384 + t] = rne_bf16(Wo[t]);
}

__global__ __launch_bounds__(512, 2)
void edge_attn_kernel(const float* __restrict__ ef,
                      const unsigned short* __restrict__ wbf,
                      const float* __restrict__ bq, const float* __restrict__ bk,
                      const float* __restrict__ bv1, const float* __restrict__ bv2,
                      const float* __restrict__ bo,
                      float* __restrict__ out) {
  // K rows (j-major) swizzled: elem (j,o) at j*128 + (((o>>3) ^ (j&15))<<3) + (o&7)
  __shared__ unsigned short Kb[256 * 128];
  // V2 transposed (d-major) swizzled: elem (j,d) at d*256 + (((j>>3) ^ (d&15))<<3) + (j&7)
  __shared__ unsigned short V2t[128 * 256];

  const int tid  = threadIdx.x;
  const int lane = tid & 63;
  const int wv   = tid >> 6;    // wave 0..7
  const int lc   = lane & 15;
  const int q4   = lane >> 4;
  const int bb   = blockIdx.x >> 8;
  const int lb   = blockIdx.x & 255;

  const unsigned short* WqB  = wbf;
  const unsigned short* WkB  = wbf + 16384;
  const unsigned short* Wv1B = wbf + 2 * 16384;
  const unsigned short* Wv2B = wbf + 3 * 16384;
  const unsigned short* WoB  = wbf + 4 * 16384;

  const f32x4 Z4 = {0.f, 0.f, 0.f, 0.f};
  const int jA = wv * 16;         // tile A rows (phase1 j / phase2 i)
  const int jB = wv * 16 + 128;   // tile B rows

  // ---------------- Phase 1: K/V2 for both j-tiles into LDS -----------------
  {
    const float* Frow = ef + ((size_t)(bb * 256 + lb)) * (256 * 128);
    bf16x8 aFA[4], aFB[4];
    {
      const float* rpA = Frow + (jA + lc) * 128 + q4 * 8;
      const float* rpB = Frow + (jB + lc) * 128 + q4 * 8;
      #pragma unroll
      for (int kc = 0; kc < 4; ++kc) {
        aFA[kc] = cvt_frag(rpA + kc * 32);
        aFB[kc] = cvt_frag(rpB + kc * 32);
      }
    }

    f32x4 aKA[8], aVA[8], aKB[8], aVB[8];
    #pragma unroll
    for (int n = 0; n < 8; ++n) { aKA[n] = Z4; aVA[n] = Z4; aKB[n] = Z4; aVB[n] = Z4; }
    #pragma unroll
    for (int kc = 0; kc < 4; ++kc) {
      #pragma unroll
      for (int n = 0; n < 8; ++n) {
        bf16x8 bwk = *(const bf16x8*)(WkB  + (n * 16 + lc) * 128 + kc * 32 + q4 * 8);
        bf16x8 bwv = *(const bf16x8*)(Wv2B + (n * 16 + lc) * 128 + kc * 32 + q4 * 8);
        aKA[n] = MFMA(aFA[kc], bwk, aKA[n]);
        aKB[n] = MFMA(aFB[kc], bwk, aKB[n]);
        aVA[n] = MFMA(aFA[kc], bwv, aVA[n]);
        aVB[n] = MFMA(aFB[kc], bwv, aVB[n]);
      }
    }
    #pragma unroll
    for (int n = 0; n < 8; ++n) {
      const int o = n * 16 + lc;
      const float bkv = bk[o];
      const float bvv = bv2[o];
      #pragma unroll
      for (int r = 0; r < 4; ++r) {
        const int ja = jA + q4 * 4 + r;
        const int jb = jB + q4 * 4 + r;
        Kb[ja * 128 + (((o >> 3) ^ (ja & 15)) << 3) + (o & 7)] = rne_bf16(aKA[n][r] + bkv);
        Kb[jb * 128 + (((o >> 3) ^ (jb & 15)) << 3) + (o & 7)] = rne_bf16(aKB[n][r] + bkv);
        V2t[o * 256 + (((ja >> 3) ^ lc) << 3) + (ja & 7)]      = rne_bf16(aVA[n][r] + bvv);
        V2t[o * 256 + (((jb >> 3) ^ lc) << 3) + (jb & 7)]      = rne_bf16(aVB[n][r] + bvv);
      }
    }
  }
  __syncthreads();

  // ---------------- Phase 2: two i-tiles per wave, lockstep -----------------
  const float scale = 0.08838834764831845f;  // 1/sqrt(128)

  // E rows for both tiles (strided gather; 16 independent loads pipeline)
  bf16x8 aEA[4], aEB[4];
  {
    const float* rpA = ef + (((size_t)(bb * 256 + jA + lc)) * 256 + lb) * 128 + q4 * 8;
    const float* rpB = ef + (((size_t)(bb * 256 + jB + lc)) * 256 + lb) * 128 + q4 * 8;
    f32x4 eA[8], eB[8];
    #pragma unroll
    for (int kc = 0; kc < 4; ++kc) {
      eA[2 * kc]     = *(const f32x4*)(rpA + kc * 32);
      eA[2 * kc + 1] = *(const f32x4*)(rpA + kc * 32 + 4);
      eB[2 * kc]     = *(const f32x4*)(rpB + kc * 32);
      eB[2 * kc + 1] = *(const f32x4*)(rpB + kc * 32 + 4);
    }
    #pragma unroll
    for (int kc = 0; kc < 4; ++kc) {
      U8 u;
      u.w[0] = cvt_pk(eA[2 * kc][0], eA[2 * kc][1]);
      u.w[1] = cvt_pk(eA[2 * kc][2], eA[2 * kc][3]);
      u.w[2] = cvt_pk(eA[2 * kc + 1][0], eA[2 * kc + 1][1]);
      u.w[3] = cvt_pk(eA[2 * kc + 1][2], eA[2 * kc + 1][3]);
      aEA[kc] = u.v;
      u.w[0] = cvt_pk(eB[2 * kc][0], eB[2 * kc][1]);
      u.w[1] = cvt_pk(eB[2 * kc][2], eB[2 * kc][3]);
      u.w[2] = cvt_pk(eB[2 * kc + 1][0], eB[2 * kc + 1][1]);
      u.w[3] = cvt_pk(eB[2 * kc + 1][2], eB[2 * kc + 1][3]);
      aEB[kc] = u.v;
    }
  }

  // Q^T projection for both tiles (shared Wq frags)
  f32x4 QtA[8], QtB[8];
  #pragma unroll
  for (int nt = 0; nt < 8; ++nt) { QtA[nt] = Z4; QtB[nt] = Z4; }
  #pragma unroll
  for (int kc = 0; kc < 4; ++kc) {
    #pragma unroll
    for (int nt = 0; nt < 8; ++nt) {
      bf16x8 aW = *(const bf16x8*)(WqB + (nt * 16 + lc) * 128 + kc * 32 + q4 * 8);
      QtA[nt] = MFMA(aW, aEA[kc], QtA[nt]);
      QtB[nt] = MFMA(aW, aEB[kc], QtB[nt]);
    }
  }
  // bias + scale, pack to bf16 pairs (pair = adjacent o)
  unsigned int qA01[8], qA23[8], qB01[8], qB23[8];
  #pragma unroll
  for (int nt = 0; nt < 8; ++nt) {
    f32x4 b4 = *(const f32x4*)(bq + nt * 16 + q4 * 4);
    qA01[nt] = cvt_pk((QtA[nt][0] + b4[0]) * scale, (QtA[nt][1] + b4[1]) * scale);
    qA23[nt] = cvt_pk((QtA[nt][2] + b4[2]) * scale, (QtA[nt][3] + b4[3]) * scale);
    qB01[nt] = cvt_pk((QtB[nt][0] + b4[0]) * scale, (QtB[nt][1] + b4[1]) * scale);
    qB23[nt] = cvt_pk((QtB[nt][2] + b4[2]) * scale, (QtB[nt][3] + b4[3]) * scale);
  }

  const int sa = ((2 * q4) & 3) * 16 + lc;
  const int sb = ((2 * q4 + 1) & 3) * 16 + lc;
  const bool hi = (q4 >= 2);

  bf16x8 bQA[4], bQB[4];
  #pragma unroll
  for (int kc = 0; kc < 4; ++kc) {
    bQA[kc] = xpose(qA01[2 * kc], qA01[2 * kc + 1], qA23[2 * kc], qA23[2 * kc + 1], sa, sb, hi);
    bQB[kc] = xpose(qB01[2 * kc], qB01[2 * kc + 1], qB23[2 * kc], qB23[2 * kc + 1], sa, sb, hi);
  }

  // S^T = mfma(K, Q) for both tiles — K frags shared
  f32x4 SA[16], SB[16];
  #pragma unroll
  for (int jt = 0; jt < 16; ++jt) { SA[jt] = Z4; SB[jt] = Z4; }
  #pragma unroll
  for (int kc = 0; kc < 4; ++kc) {
    #pragma unroll
    for (int jt = 0; jt < 16; ++jt) {
      bf16x8 bK = *(const bf16x8*)(Kb + (jt * 16 + lc) * 128 + (((kc * 4 + q4) ^ lc) << 3));
      SA[jt] = MFMA(bK, bQA[kc], SA[jt]);
      SB[jt] = MFMA(bK, bQB[kc], SB[jt]);
    }
  }

  // softmax both tiles (B's VALU overlaps nothing-MFMA; A's overlaps SB tail)
  unsigned int pA01[16], pA23[16], pB01[16], pB23[16];
  softmax_pack(SA, pA01, pA23);
  softmax_pack(SB, pB01, pB23);

  bf16x8 aPA[8], aPB[8];
  #pragma unroll
  for (int kc = 0; kc < 8; ++kc) {
    aPA[kc] = xpose(pA01[2 * kc], pA01[2 * kc + 1], pA23[2 * kc], pA23[2 * kc + 1], sa, sb, hi);
    aPB[kc] = xpose(pB01[2 * kc], pB01[2 * kc + 1], pB23[2 * kc], pB23[2 * kc + 1], sa, sb, hi);
  }

  // Ct = mfma(V2^T, P) for both tiles — V2 frags shared
  f32x4 CA[8], CB[8];
  #pragma unroll
  for (int nt = 0; nt < 8; ++nt) { CA[nt] = Z4; CB[nt] = Z4; }
  #pragma unroll
  for (int kc = 0; kc < 8; ++kc) {
    #pragma unroll
    for (int nt = 0; nt < 8; ++nt) {
      bf16x8 bV = *(const bf16x8*)(V2t + (nt * 16 + lc) * 256 + (((kc * 4 + q4) ^ lc) << 3));
      CA[nt] = MFMA(bV, aPA[kc], CA[nt]);
      CB[nt] = MFMA(bV, aPB[kc], CB[nt]);
    }
  }

  // V1^T projection (shared Wv1 frags), then Ct *= (V1^T + bv1)
  f32x4 VA[8], VB[8];
  #pragma unroll
  for (int nt = 0; nt < 8; ++nt) { VA[nt] = Z4; VB[nt] = Z4; }
  #pragma unroll
  for (int kc = 0; kc < 4; ++kc) {
    #pragma unroll
    for (int nt = 0; nt < 8; ++nt) {
      bf16x8 aW = *(const bf16x8*)(Wv1B + (nt * 16 + lc) * 128 + kc * 32 + q4 * 8);
      VA[nt] = MFMA(aW, aEA[kc], VA[nt]);
      VB[nt] = MFMA(aW, aEB[kc], VB[nt]);
    }
  }
  #pragma unroll
  for (int nt = 0; nt < 8; ++nt) {
    f32x4 b4 = *(const f32x4*)(bv1 + nt * 16 + q4 * 4);
    #pragma unroll
    for (int r = 0; r < 4; ++r) {
      CA[nt][r] *= (VA[nt][r] + b4[r]);
      CB[nt][r] *= (VB[nt][r] + b4[r]);
    }
  }

  // pack ctx pairs and transpose to A-frags
  unsigned int cA01[8], cA23[8], cB01[8], cB23[8];
  #pragma unroll
  for (int nt = 0; nt < 8; ++nt) {
    cA01[nt] = cvt_pk(CA[nt][0], CA[nt][1]);
    cA23[nt] = cvt_pk(CA[nt][2], CA[nt][3]);
    cB01[nt] = cvt_pk(CB[nt][0], CB[nt][1]);
    cB23[nt] = cvt_pk(CB[nt][2], CB[nt][3]);
  }
  bf16x8 aCA[4], aCB[4];
  #pragma unroll
  for (int kc = 0; kc < 4; ++kc) {
    aCA[kc] = xpose(cA01[2 * kc], cA01[2 * kc + 1], cA23[2 * kc], cA23[2 * kc + 1], sa, sb, hi);
    aCB[kc] = xpose(cB01[2 * kc], cB01[2 * kc + 1], cB23[2 * kc], cB23[2 * kc + 1], sa, sb, hi);
  }

  // O = ctx @ Wo^T + bo (shared Wo frags; C-layout, coalesced store)
  f32x4 OA[8], OB[8];
  #pragma unroll
  for (int n = 0; n < 8; ++n) { OA[n] = Z4; OB[n] = Z4; }
  #pragma unroll
  for (int kc = 0; kc < 4; ++kc) {
    #pragma unroll
    for (int n = 0; n < 8; ++n) {
      bf16x8 bw = *(const bf16x8*)(WoB + (n * 16 + lc) * 128 + kc * 32 + q4 * 8);
      OA[n] = MFMA(aCA[kc], bw, OA[n]);
      OB[n] = MFMA(aCB[kc], bw, OB[n]);
    }
  }
  #pragma unroll
  for (int n = 0; n < 8; ++n) {
    const float bov = bo[n * 16 + lc];
    #pragma unroll
    for (int r = 0; r < 4; ++r) {
      const int ia = jA + q4 * 4 + r;
      const int ib = jB + q4 * 4 + r;
      out[(((size_t)(bb * 256 + ia)) * 256 + lb) * 128 + n * 16 + lc] = OA[n][r] + bov;
      out[(((size_t)(bb * 256 + ib)) * 256 + lb) * 128 + n * 16 + lc] = OB[n][r] + bov;
    }
  }
}

extern "C" void kernel_launch(void* const* d_in, const int* in_sizes, int n_in,
                              void* d_out, int out_size, void* d_ws, size_t ws_size,
                              hipStream_t stream) {
  const float* ef   = (const float*)d_in[0];
  const float* Wq   = (const float*)d_in[1];
  const float* bqp  = (const float*)d_in[2];
  const float* Wk   = (const float*)d_in[3];
  const float* bkp  = (const float*)d_in[4];
  const float* Wv1  = (const float*)d_in[5];
  const float* bv1p = (const float*)d_in[6];
  const float* Wv2  = (const float*)d_in[7];
  const float* bv2p = (const float*)d_in[8];
  const float* Wo   = (const float*)d_in[9];
  const float* bop  = (const float*)d_in[10];
  unsigned short* wbf = (unsigned short*)d_ws;   // 5 * 128*128 bf16 = 160 KB

  cvt_weights<<<64, 256, 0, stream>>>(Wq, Wk, Wv1, Wv2, Wo, wbf);
  edge_attn_kernel<<<512, 512, 0, stream>>>(ef, wbf, bqp, bkp, bv1p, bv2p, bop,
                                            (float*)d_out);
}